// Round 1
// baseline (8119.348 us; speedup 1.0000x reference)
//
#include <hip/hip_runtime.h>
#include <math.h>

// Problem constants
static constexpr int BB = 64, TT = 26, EE = 300, HH = 1024;
static constexpr int FEAT = 2048, SS = 49;
static constexpr int D1 = 245000, D2 = 5000;
static constexpr int MOUT = 1000;
static constexpr int VOCAB = 3000;

// ---------------------------------------------------------------------------
// Generic fp32 GEMM: C[M,N] = act( A(M,K) * B(N,K)^T + bias1 + bias2 )
// A rows contiguous with stride lda; B rows contiguous with stride ldb.
// ---------------------------------------------------------------------------
template <int BM, int BN, int BK, int TM, int TN, bool RELU>
__global__ void gemm_abt(const float* __restrict__ A, const float* __restrict__ B,
                         const float* __restrict__ bias1, const float* __restrict__ bias2,
                         float* __restrict__ C,
                         int M, int N, int K, int lda, int ldb, int ldc) {
    constexpr int THREADS = (BM / TM) * (BN / TN);
    __shared__ float As[BK][BM + 1];
    __shared__ float Bs[BK][BN + 1];
    const int tid = threadIdx.x;
    const int tx = tid % (BN / TN);
    const int ty = tid / (BN / TN);
    const int block_m = blockIdx.y * BM;
    const int block_n = blockIdx.x * BN;
    float acc[TM][TN];
#pragma unroll
    for (int i = 0; i < TM; i++)
#pragma unroll
        for (int j = 0; j < TN; j++) acc[i][j] = 0.f;

    for (int k0 = 0; k0 < K; k0 += BK) {
        for (int i = tid; i < BM * BK; i += THREADS) {
            int m = i / BK, kk = i % BK;
            int gm = block_m + m, gk = k0 + kk;
            As[kk][m] = (gm < M && gk < K) ? A[(size_t)gm * lda + gk] : 0.f;
        }
        for (int i = tid; i < BN * BK; i += THREADS) {
            int n = i / BK, kk = i % BK;
            int gn = block_n + n, gk = k0 + kk;
            Bs[kk][n] = (gn < N && gk < K) ? B[(size_t)gn * ldb + gk] : 0.f;
        }
        __syncthreads();
#pragma unroll
        for (int kk = 0; kk < BK; kk++) {
            float a[TM], b[TN];
#pragma unroll
            for (int i = 0; i < TM; i++) a[i] = As[kk][ty * TM + i];
#pragma unroll
            for (int j = 0; j < TN; j++) b[j] = Bs[kk][tx * TN + j];
#pragma unroll
            for (int i = 0; i < TM; i++)
#pragma unroll
                for (int j = 0; j < TN; j++) acc[i][j] += a[i] * b[j];
        }
        __syncthreads();
    }
#pragma unroll
    for (int i = 0; i < TM; i++) {
        int gm = block_m + ty * TM + i;
        if (gm >= M) continue;
#pragma unroll
        for (int j = 0; j < TN; j++) {
            int gn = block_n + tx * TN + j;
            if (gn >= N) continue;
            float v = acc[i][j];
            if (bias1) v += bias1[gn];
            if (bias2) v += bias2[gn];
            if (RELU) v = fmaxf(v, 0.f);
            C[(size_t)gm * ldc + gn] = v;
        }
    }
}

// ---------------------------------------------------------------------------
// LSTM pointwise: gates -> (h, c), torch gate order i,f,g,o
// ---------------------------------------------------------------------------
__global__ void lstm_pointwise(const float* __restrict__ xW, const float* __restrict__ gt,
                               float* __restrict__ h, float* __restrict__ c,
                               float* __restrict__ hs, int t) {
    int idx = blockIdx.x * blockDim.x + threadIdx.x;  // b*H + hh
    if (idx >= BB * HH) return;
    int b = idx >> 10, hh = idx & (HH - 1);
    size_t rx = ((size_t)b * TT + t) * 4 * HH;
    size_t rg = (size_t)b * 4 * HH;
    float gi = xW[rx + hh] + gt[rg + hh];
    float gf = xW[rx + HH + hh] + gt[rg + HH + hh];
    float gg = xW[rx + 2 * HH + hh] + gt[rg + 2 * HH + hh];
    float go = xW[rx + 3 * HH + hh] + gt[rg + 3 * HH + hh];
    float si = 1.f / (1.f + expf(-gi));
    float sf = 1.f / (1.f + expf(-gf));
    float so = 1.f / (1.f + expf(-go));
    float tg = tanhf(gg);
    float cn = sf * c[idx] + si * tg;
    float hn = so * tanhf(cn);
    c[idx] = cn;
    h[idx] = hn;
    hs[((size_t)t * BB + b) * HH + hh] = hn;
}

// qa2[b,g,t] = sum_o Wq2[g,o]*qa[(t*B+b),o] + bq2[g]
__global__ void qa2_kernel(const float* __restrict__ qa, const float* __restrict__ Wq2,
                           const float* __restrict__ bq2, float* __restrict__ out) {
    int tid = blockIdx.x * blockDim.x + threadIdx.x;
    if (tid >= BB * 2 * TT) return;
    int t = tid % TT;
    int bg = tid / TT;
    int g = bg & 1;
    const float* arow = qa + ((size_t)t * BB + (bg >> 1)) * 512;
    const float* wrow = Wq2 + g * 512;
    float acc = bq2[g];
    for (int o = 0; o < 512; o++) acc += wrow[o] * arow[o];
    out[tid] = acc;
}

// ia2[b,g,s] = sum_o Wi2[g,o]*ia[(b*S+s),o] + bi2[g]
__global__ void ia2_kernel(const float* __restrict__ ia, const float* __restrict__ Wi2,
                           const float* __restrict__ bi2, float* __restrict__ out) {
    int tid = blockIdx.x * blockDim.x + threadIdx.x;
    if (tid >= BB * 2 * SS) return;
    int s = tid % SS;
    int bg = tid / SS;
    int g = bg & 1;
    int b = bg >> 1;
    const float* arow = ia + ((size_t)b * SS + s) * 512;
    const float* wrow = Wi2 + g * 512;
    float acc = bi2[g];
    for (int o = 0; o < 512; o++) acc += wrow[o] * arow[o];
    out[tid] = acc;
}

// in-place row softmax, one thread per row (tiny rows)
__global__ void softmax_small(float* __restrict__ x, int rows, int len) {
    int r = blockIdx.x * blockDim.x + threadIdx.x;
    if (r >= rows) return;
    float* xr = x + (size_t)r * len;
    float mx = -1e30f;
    for (int i = 0; i < len; i++) mx = fmaxf(mx, xr[i]);
    float s = 0.f;
    for (int i = 0; i < len; i++) s += expf(xr[i] - mx);
    float inv = 1.f / s;
    for (int i = 0; i < len; i++) xr[i] = expf(xr[i] - mx) * inv;
}

// q_feat[b, g*H+h] = sum_t qatt[b,g,t]*hs[t,b,h]
__global__ void qfeat_kernel(const float* __restrict__ qatt, const float* __restrict__ hs,
                             float* __restrict__ qf) {
    int idx = blockIdx.x * blockDim.x + threadIdx.x;  // b*2048 + g*1024 + h
    if (idx >= BB * 2048) return;
    int b = idx >> 11;
    int gh = idx & 2047;
    int g = gh >> 10;
    int hh = gh & 1023;
    float acc = 0.f;
    for (int t = 0; t < TT; t++)
        acc += qatt[((size_t)b * 2 + g) * TT + t] * hs[((size_t)t * BB + b) * HH + hh];
    qf[idx] = acc;
}

// MCB1 scatter, folded over FACTOR: atil[b, (p-49f) mod D1] += v, f=0..4
__global__ void mcb1_scatter(const float* __restrict__ img_feat, const int* __restrict__ h1x,
                             const int* __restrict__ s1x, float* __restrict__ atil) {
    size_t tid = (size_t)blockIdx.x * blockDim.x + threadIdx.x;  // (b*49+s)*2048+f
    if (tid >= (size_t)BB * SS * FEAT) return;
    int f = (int)(tid & 2047);
    int bs = (int)(tid >> 11);
    int s = bs % SS;
    int b = bs / SS;
    float v = img_feat[tid];  // img_feat[(b,c1,c2,f)] == x[b, f*49+s]
    int n = f * SS + s;
    v *= (float)(2 * s1x[n] - 1);
    int p = h1x[n];
    float* ab = atil + (size_t)b * D1;
#pragma unroll
    for (int f5 = 0; f5 < 5; f5++) {
        int t = p - 49 * f5;
        if (t < 0) t += D1;
        atomicAdd(&ab[t], v);
    }
}

// MCB1 gather conv: iq[b,s,m] = sum_j v_j * atil[b, (245m+s-p_j) mod D1]
__global__ void mcb1_gather(const float* __restrict__ atil, const float* __restrict__ qf,
                            const int* __restrict__ h1q, const int* __restrict__ s1q,
                            float* __restrict__ iq) {
    __shared__ int sp[2048];
    __shared__ float sv[2048];
    int b = blockIdx.y;
    const float* qb = qf + (size_t)b * 2048;
    for (int j = threadIdx.x; j < 2048; j += blockDim.x) {
        sp[j] = h1q[j];
        sv[j] = qb[j] * (float)(2 * s1q[j] - 1);
    }
    __syncthreads();
    int o = blockIdx.x * blockDim.x + threadIdx.x;  // o = m*49 + s
    if (o >= MOUT * SS) return;
    int m = o / SS, s = o % SS;
    int tb = 245 * m + s;
    const float* ab = atil + (size_t)b * D1;
    float acc = 0.f;
#pragma unroll 4
    for (int j = 0; j < 2048; j++) {
        int addr = tb - sp[j];
        if (addr < 0) addr += D1;
        acc += sv[j] * ab[addr];
    }
    iq[((size_t)b * SS + s) * MOUT + m] = acc;
}

// signed sqrt + global L2 normalize over n elements per batch row (one block per b)
__global__ void ssqrt_l2norm(float* __restrict__ x, int n) {
    __shared__ float red[256];
    __shared__ float inv_s;
    int b = blockIdx.x;
    float* xb = x + (size_t)b * n;
    float ss = 0.f;
    for (int i = threadIdx.x; i < n; i += 256) {
        float v = xb[i];
        float y = (v >= 0.f) ? sqrtf(v) : -sqrtf(-v);
        xb[i] = y;
        ss += y * y;
    }
    red[threadIdx.x] = ss;
    __syncthreads();
    for (int s = 128; s > 0; s >>= 1) {
        if (threadIdx.x < s) red[threadIdx.x] += red[threadIdx.x + s];
        __syncthreads();
    }
    if (threadIdx.x == 0) inv_s = 1.f / fmaxf(sqrtf(red[0]), 1e-12f);
    __syncthreads();
    float inv = inv_s;
    for (int i = threadIdx.x; i < n; i += 256) xb[i] *= inv;
}

// i_feat[b, g*FEAT+f] = sum_s iatt[b,g,s] * img_feat[(b*49+s)*2048+f]
__global__ void ifeat_kernel(const float* __restrict__ iatt, const float* __restrict__ img_feat,
                             float* __restrict__ ifeat) {
    int idx = blockIdx.x * blockDim.x + threadIdx.x;  // b*4096 + g*2048 + f
    if (idx >= BB * 4096) return;
    int b = idx >> 12;
    int gf = idx & 4095;
    int g = gf >> 11;
    int f = gf & 2047;
    float acc = 0.f;
    for (int s = 0; s < SS; s++)
        acc += iatt[((size_t)b * 2 + g) * SS + s] * img_feat[((size_t)b * SS + s) * FEAT + f];
    ifeat[idx] = acc;
}

// MCB2 scatter folded: atil2[b, (p-f) mod D2] += v, f=0..4
__global__ void mcb2_scatter(const float* __restrict__ ifeat, const int* __restrict__ h2i,
                             const int* __restrict__ s2i, float* __restrict__ atil2) {
    int tid = blockIdx.x * blockDim.x + threadIdx.x;  // b*4096 + i
    if (tid >= BB * 4096) return;
    int i = tid & 4095;
    int b = tid >> 12;
    float v = ifeat[tid] * (float)(2 * s2i[i] - 1);
    int p = h2i[i];
    float* ab = atil2 + (size_t)b * D2;
#pragma unroll
    for (int f = 0; f < 5; f++) {
        int t = p - f;
        if (t < 0) t += D2;
        atomicAdd(&ab[t], v);
    }
}

// MCB2 gather: z[b,m] = sum_j v_j * atil2[b, (5m - p_j) mod D2]
__global__ void mcb2_gather(const float* __restrict__ atil2, const float* __restrict__ qf,
                            const int* __restrict__ h2q, const int* __restrict__ s2q,
                            float* __restrict__ z) {
    __shared__ float sa[D2];
    __shared__ int sp[2048];
    __shared__ float sv[2048];
    int b = blockIdx.y;
    for (int i = threadIdx.x; i < D2; i += 256) sa[i] = atil2[(size_t)b * D2 + i];
    const float* qb = qf + (size_t)b * 2048;
    for (int j = threadIdx.x; j < 2048; j += 256) {
        sp[j] = h2q[j];
        sv[j] = qb[j] * (float)(2 * s2q[j] - 1);
    }
    __syncthreads();
    int m = blockIdx.x * 256 + threadIdx.x;
    if (m >= MOUT) return;
    int base = 5 * m + D2;
    float acc = 0.f;
#pragma unroll 4
    for (int j = 0; j < 2048; j++) {
        int addr = base - sp[j];
        if (addr >= D2) addr -= D2;
        acc += sv[j] * sa[addr];
    }
    z[(size_t)b * MOUT + m] = acc;
}

// row softmax, one block per row, n up to a few thousand
__global__ void softmax_rows(const float* __restrict__ logits, float* __restrict__ out, int n) {
    __shared__ float red[256];
    int b = blockIdx.x;
    const float* xr = logits + (size_t)b * n;
    float* orow = out + (size_t)b * n;
    float mx = -1e30f;
    for (int i = threadIdx.x; i < n; i += 256) mx = fmaxf(mx, xr[i]);
    red[threadIdx.x] = mx;
    __syncthreads();
    for (int s = 128; s > 0; s >>= 1) {
        if (threadIdx.x < s) red[threadIdx.x] = fmaxf(red[threadIdx.x], red[threadIdx.x + s]);
        __syncthreads();
    }
    mx = red[0];
    __syncthreads();
    float sum = 0.f;
    for (int i = threadIdx.x; i < n; i += 256) sum += expf(xr[i] - mx);
    red[threadIdx.x] = sum;
    __syncthreads();
    for (int s = 128; s > 0; s >>= 1) {
        if (threadIdx.x < s) red[threadIdx.x] += red[threadIdx.x + s];
        __syncthreads();
    }
    float inv = 1.f / red[0];
    for (int i = threadIdx.x; i < n; i += 256) orow[i] = expf(xr[i] - mx) * inv;
}

extern "C" void kernel_launch(void* const* d_in, const int* in_sizes, int n_in,
                              void* d_out, int out_size, void* d_ws, size_t ws_size,
                              hipStream_t stream) {
    (void)in_sizes; (void)n_in; (void)out_size; (void)ws_size;
    const float* ques = (const float*)d_in[0];
    const float* img  = (const float*)d_in[1];
    const float* W_ih = (const float*)d_in[2];
    const float* W_hh = (const float*)d_in[3];
    const float* b_ih = (const float*)d_in[4];
    const float* b_hh = (const float*)d_in[5];
    const float* Wq1  = (const float*)d_in[6];
    const float* bq1  = (const float*)d_in[7];
    const float* Wq2  = (const float*)d_in[8];
    const float* bq2  = (const float*)d_in[9];
    const float* Wi1  = (const float*)d_in[10];
    const float* bi1  = (const float*)d_in[11];
    const float* Wi2  = (const float*)d_in[12];
    const float* bi2  = (const float*)d_in[13];
    const float* Wp   = (const float*)d_in[14];
    const float* bp   = (const float*)d_in[15];
    const int* h1x = (const int*)d_in[16];
    const int* s1x = (const int*)d_in[17];
    const int* h1q = (const int*)d_in[18];
    const int* s1q = (const int*)d_in[19];
    const int* h2i = (const int*)d_in[20];
    const int* s2i = (const int*)d_in[21];
    const int* h2q = (const int*)d_in[22];
    const int* s2q = (const int*)d_in[23];
    float* out = (float*)d_out;

    // workspace layout (floats). xW aliases atil (xW dead before MCB1 zero-init).
    float* ws = (float*)d_ws;
    size_t off = 0;
    float* xw    = ws;                       // 26*64*4096 = 6,815,744
    float* atil  = ws;                       // 64*245000  = 15,680,000
    off += 15680000;
    float* hs    = ws + off; off += (size_t)TT * BB * HH;   // 1,703,936
    float* hcur  = ws + off; off += BB * HH;                // 65,536
    float* ccur  = ws + off; off += BB * HH;                // 65,536
    float* gt    = ws + off; off += BB * 4 * HH;            // 262,144
    float* qa    = ws + off; off += (size_t)TT * BB * 512;  // 851,968
    float* qatt  = ws + off; off += 4096;
    float* qf    = ws + off; off += BB * 2048;              // 131,072
    float* iq    = ws + off; off += (size_t)BB * SS * MOUT; // 3,136,000
    float* ia    = ws + off; off += (size_t)BB * SS * 512;  // 1,605,632
    float* iatt  = ws + off; off += 8192;
    float* ifeat = ws + off; off += BB * 4096;              // 262,144
    float* atil2 = ws + off; off += BB * D2;                // 320,000
    float* z     = ws + off; off += BB * MOUT;              // 64,000
    float* logits= ws + off; off += (size_t)BB * VOCAB;     // 192,000

    // ---- LSTM ----
    hipMemsetAsync(hcur, 0, (size_t)BB * HH * 4, stream);
    hipMemsetAsync(ccur, 0, (size_t)BB * HH * 4, stream);
    {   // xW[(b*T+t), g] = ques(b,t,:) . W_ih(g,:) + b_ih + b_hh
        dim3 grid(4096 / 64, (BB * TT + 63) / 64);
        gemm_abt<64, 64, 16, 4, 4, false><<<grid, 256, 0, stream>>>(
            ques, W_ih, b_ih, b_hh, xw, BB * TT, 4 * HH, EE, EE, EE, 4 * HH);
    }
    for (int t = 0; t < TT; t++) {
        dim3 grid(4096 / 64, 4);
        gemm_abt<16, 64, 16, 2, 2, false><<<grid, 256, 0, stream>>>(
            hcur, W_hh, nullptr, nullptr, gt, BB, 4 * HH, HH, HH, HH, 4 * HH);
        lstm_pointwise<<<(BB * HH + 255) / 256, 256, 0, stream>>>(xw, gt, hcur, ccur, hs, t);
    }
    // ---- question attention ----
    {   // qa[(t*B+b), o] = relu(hs(t,b,:) . Wq1(o,:) + bq1)
        dim3 grid(512 / 64, (TT * BB) / 64);
        gemm_abt<64, 64, 16, 4, 4, true><<<grid, 256, 0, stream>>>(
            hs, Wq1, bq1, nullptr, qa, TT * BB, 512, HH, HH, HH, 512);
    }
    qa2_kernel<<<(BB * 2 * TT + 255) / 256, 256, 0, stream>>>(qa, Wq2, bq2, qatt);
    softmax_small<<<1, 128, 0, stream>>>(qatt, BB * 2, TT);
    qfeat_kernel<<<(BB * 2048) / 256, 256, 0, stream>>>(qatt, hs, qf);
    // ---- MCB1 + image attention ----
    hipMemsetAsync(atil, 0, (size_t)BB * D1 * 4, stream);
    mcb1_scatter<<<(BB * SS * FEAT) / 256, 256, 0, stream>>>(img, h1x, s1x, atil);
    {
        dim3 grid((MOUT * SS + 255) / 256, BB);
        mcb1_gather<<<grid, 256, 0, stream>>>(atil, qf, h1q, s1q, iq);
    }
    ssqrt_l2norm<<<BB, 256, 0, stream>>>(iq, MOUT * SS);
    {   // ia[(b*S+s), o] = relu(iq(b,s,:) . Wi1(o,:) + bi1)
        dim3 grid(512 / 64, (BB * SS + 63) / 64);
        gemm_abt<64, 64, 16, 4, 4, true><<<grid, 256, 0, stream>>>(
            iq, Wi1, bi1, nullptr, ia, BB * SS, 512, MOUT, MOUT, MOUT, 512);
    }
    ia2_kernel<<<(BB * 2 * SS + 255) / 256, 256, 0, stream>>>(ia, Wi2, bi2, iatt);
    softmax_small<<<1, 128, 0, stream>>>(iatt, BB * 2, SS);
    ifeat_kernel<<<(BB * 4096) / 256, 256, 0, stream>>>(iatt, img, ifeat);
    // ---- MCB2 + classifier ----
    hipMemsetAsync(atil2, 0, (size_t)BB * D2 * 4, stream);
    mcb2_scatter<<<(BB * 4096) / 256, 256, 0, stream>>>(ifeat, h2i, s2i, atil2);
    {
        dim3 grid(4, BB);
        mcb2_gather<<<grid, 256, 0, stream>>>(atil2, qf, h2q, s2q, z);
    }
    ssqrt_l2norm<<<BB, 256, 0, stream>>>(z, MOUT);
    {
        dim3 grid((VOCAB + 63) / 64, 4);
        gemm_abt<16, 64, 16, 2, 2, false><<<grid, 256, 0, stream>>>(
            z, Wp, bp, nullptr, logits, BB, VOCAB, MOUT, MOUT, MOUT, VOCAB);
    }
    softmax_rows<<<BB, 256, 0, stream>>>(logits, out, VOCAB);
}